// Round 1
// baseline (1295.599 us; speedup 1.0000x reference)
//
#include <hip/hip_runtime.h>

typedef unsigned short u16;
typedef __attribute__((ext_vector_type(4))) float f32x4;
typedef __attribute__((ext_vector_type(8))) short s16x8;

#define T_TOK 8192
#define HD    1024
#define ID    4096
#define NE    8
#define AK    (T_TOK * 2)      // total assignments (top-2)
#define APAD  (AK + 128)       // slack rows so padded tile reads stay in-buffer

__device__ __forceinline__ u16 f2bf(float f) {
  unsigned u = __builtin_bit_cast(unsigned, f);
  u += 0x7FFFu + ((u >> 16) & 1u);   // round-to-nearest-even
  return (u16)(u >> 16);
}

__device__ __forceinline__ void gld16(u16* lds, const u16* g) {
  __builtin_amdgcn_global_load_lds(
      (const __attribute__((address_space(1))) unsigned int*)g,
      (__attribute__((address_space(3))) unsigned int*)lds, 16, 0, 0);
}

// ---------------- routing ----------------

__global__ void k_init(int* counts) {
  if (threadIdx.x < NE) counts[threadIdx.x] = 0;
}

__global__ __launch_bounds__(256) void k_router(
    const float* __restrict__ x, const float* __restrict__ wg,
    int* __restrict__ tidx, float* __restrict__ tw, int* __restrict__ counts) {
  __shared__ float wgs[NE * HD];            // transposed [e][h] for conflict-free reads
  int tid = threadIdx.x;
  for (int i = tid; i < NE * HD; i += 256) {
    int h = i >> 3, e = i & 7;
    wgs[e * HD + h] = wg[i];
  }
  __syncthreads();
  int lane = tid & 63, wid = tid >> 6;
  int t = blockIdx.x * 4 + wid;
  const float* xr = x + (size_t)t * HD;
  double acc[NE];
#pragma unroll
  for (int e = 0; e < NE; ++e) acc[e] = 0.0;
  for (int i = 0; i < HD / 64; ++i) {
    float xv = xr[lane + i * 64];
#pragma unroll
    for (int e = 0; e < NE; ++e)
      acc[e] += (double)xv * (double)wgs[e * HD + lane + i * 64];
  }
#pragma unroll
  for (int e = 0; e < NE; ++e)
    for (int s = 32; s >= 1; s >>= 1) acc[e] += __shfl_xor(acc[e], s, 64);
  // top-2 (first-index wins on ties, matching jax top_k)
  int e0 = 0; double m0 = acc[0];
  for (int e = 1; e < NE; ++e) if (acc[e] > m0) { m0 = acc[e]; e0 = e; }
  int e1 = -1; double m1 = -1e300;
  for (int e = 0; e < NE; ++e) if (e != e0 && acc[e] > m1) { m1 = acc[e]; e1 = e; }
  if (lane == 0) {
    double d = exp(m1 - m0);           // renormalized top-2 softmax weights
    tidx[t * 2] = e0; tidx[t * 2 + 1] = e1;
    tw[t * 2] = (float)(1.0 / (1.0 + d));
    tw[t * 2 + 1] = (float)(d / (1.0 + d));
    atomicAdd(&counts[e0], 1);
    atomicAdd(&counts[e1], 1);
  }
}

__global__ void k_offsets(const int* __restrict__ counts, int* offs, int* cursors) {
  if (threadIdx.x == 0) {
    int s = 0;
    for (int e = 0; e < NE; ++e) { offs[e] = s; s += counts[e]; }
    offs[NE] = s;
  }
  if (threadIdx.x < NE) cursors[threadIdx.x] = 0;
}

__global__ __launch_bounds__(256) void k_scatter(
    const int* __restrict__ tidx, const int* __restrict__ offs,
    int* cursors, int* __restrict__ list, int* __restrict__ pos) {
  int idx = blockIdx.x * 256 + threadIdx.x;
  if (idx >= AK) return;
  int e = tidx[idx];
  int p = atomicAdd(&cursors[e], 1);
  int a = offs[e] + p;
  list[a] = idx >> 1;
  pos[idx] = a;
}

// ---------------- fp32 -> bf16 conversion ----------------

__global__ __launch_bounds__(256) void k_cvtx(const float* __restrict__ in,
                                              u16* __restrict__ out) {
  int idx = blockIdx.x * 256 + threadIdx.x;   // one float4 each
  const float4* in4 = (const float4*)in;
  float4 v = in4[idx];
  ushort4 o;
  o.x = f2bf(v.x); o.y = f2bf(v.y); o.z = f2bf(v.z); o.w = f2bf(v.w);
  ((ushort4*)out)[idx] = o;
}

// [R][C] fp32 -> [C][R] bf16, per expert (blockIdx.z)
__global__ __launch_bounds__(256) void k_tconv(const float* __restrict__ in,
                                               u16* __restrict__ out, int R, int C) {
  __shared__ u16 tile[64][66];
  size_t base = (size_t)blockIdx.z * R * C;
  in += base; out += base;
  int r0 = blockIdx.y * 64, c0 = blockIdx.x * 64;
  int tx = threadIdx.x & 63, ty = threadIdx.x >> 6;
#pragma unroll
  for (int i = 0; i < 16; ++i) {
    int r = i * 4 + ty;
    tile[r][tx] = f2bf(in[(size_t)(r0 + r) * C + c0 + tx]);
  }
  __syncthreads();
#pragma unroll
  for (int i = 0; i < 16; ++i) {
    int c = i * 4 + ty;
    out[(size_t)(c0 + c) * R + r0 + tx] = tile[tx][c];
  }
}

// ---------------- GEMM1: hidden = silu(x@w1) * (x@w3), gathered rows ----------------
// tile 128(M) x 64(N=I) x 64(K=H); 4 waves 2x2, wave tile 64x32

__global__ __launch_bounds__(256, 2) void k_gemm1(
    const u16* __restrict__ xb, const u16* __restrict__ w1b,
    const u16* __restrict__ w3b, const int* __restrict__ list,
    const int* __restrict__ offs, u16* __restrict__ hidden) {
  int e = blockIdx.z;
  int aoff = offs[e];
  int cnt = offs[e + 1] - aoff;
  int m0 = blockIdx.y * 128;
  if (m0 >= cnt) return;
  int n0 = blockIdx.x * 64;

  __shared__ u16 As[2][128 * 64];
  __shared__ u16 B1s[2][64 * 64];
  __shared__ u16 B3s[2][64 * 64];

  int tid = threadIdx.x, lane = tid & 63, wid = tid >> 6;
  int l8 = lane >> 3, c8 = lane & 7;

  const u16* gA[4];
#pragma unroll
  for (int i = 0; i < 4; ++i) {
    int row = (i * 4 + wid) * 8 + l8;
    int rr = m0 + row; if (rr > cnt - 1) rr = cnt - 1;
    int tok = list[aoff + rr];
    gA[i] = xb + (size_t)tok * HD + c8 * 8;
  }
  const u16* gB1[2]; const u16* gB3[2];
#pragma unroll
  for (int i = 0; i < 2; ++i) {
    int n = (i * 4 + wid) * 8 + l8;
    size_t roww = ((size_t)e * ID + (n0 + n)) * HD + c8 * 8;
    gB1[i] = w1b + roww;
    gB3[i] = w3b + roww;
  }

  f32x4 acc1[4][2], acc3[4][2];
#pragma unroll
  for (int m = 0; m < 4; ++m)
#pragma unroll
    for (int n = 0; n < 2; ++n) {
      acc1[m][n] = (f32x4){0.f, 0.f, 0.f, 0.f};
      acc3[m][n] = (f32x4){0.f, 0.f, 0.f, 0.f};
    }

  auto stage = [&](int buf, int k0) {
#pragma unroll
    for (int i = 0; i < 4; ++i) gld16(&As[buf][(i * 4 + wid) * 512], gA[i] + k0);
#pragma unroll
    for (int i = 0; i < 2; ++i) {
      gld16(&B1s[buf][(i * 4 + wid) * 512], gB1[i] + k0);
      gld16(&B3s[buf][(i * 4 + wid) * 512], gB3[i] + k0);
    }
  };

  int lane15 = lane & 15, lq = lane >> 4;
  int wr = wid >> 1, wc = wid & 1;
  int arow = wr * 64, bcol = wc * 32;

  stage(0, 0);
  for (int t = 0; t < HD / 64; ++t) {
    __syncthreads();                       // drains vmcnt -> buf[t&1] staged
    if (t < HD / 64 - 1) stage((t + 1) & 1, (t + 1) * 64);
    int buf = t & 1;
#pragma unroll
    for (int kk = 0; kk < 2; ++kk) {
      int ko = kk * 32 + lq * 8;
      s16x8 a[4], b1[2], b3[2];
#pragma unroll
      for (int m = 0; m < 4; ++m)
        a[m] = *(const s16x8*)&As[buf][(arow + m * 16 + lane15) * 64 + ko];
#pragma unroll
      for (int n = 0; n < 2; ++n) {
        b1[n] = *(const s16x8*)&B1s[buf][(bcol + n * 16 + lane15) * 64 + ko];
        b3[n] = *(const s16x8*)&B3s[buf][(bcol + n * 16 + lane15) * 64 + ko];
      }
#pragma unroll
      for (int m = 0; m < 4; ++m)
#pragma unroll
        for (int n = 0; n < 2; ++n) {
          acc1[m][n] = __builtin_amdgcn_mfma_f32_16x16x32_bf16(a[m], b1[n], acc1[m][n], 0, 0, 0);
          acc3[m][n] = __builtin_amdgcn_mfma_f32_16x16x32_bf16(a[m], b3[n], acc3[m][n], 0, 0, 0);
        }
    }
  }

#pragma unroll
  for (int m = 0; m < 4; ++m)
#pragma unroll
    for (int j = 0; j < 4; ++j) {
      int grow = m0 + arow + m * 16 + lq * 4 + j;
      if (grow < cnt) {
        size_t rbase = (size_t)(aoff + grow) * ID + n0 + bcol;
#pragma unroll
        for (int n = 0; n < 2; ++n) {
          float v1 = acc1[m][n][j];
          float v3 = acc3[m][n][j];
          float s = v1 / (1.0f + __expf(-v1));
          hidden[rbase + n * 16 + lane15] = f2bf(s * v3);
        }
      }
    }
}

// ---------------- GEMM2: y = hidden @ w2 ----------------
// tile 128(M) x 128(N=H) x 64(K=I); 4 waves 2x2, wave tile 64x64

__global__ __launch_bounds__(256, 2) void k_gemm2(
    const u16* __restrict__ hidden, const u16* __restrict__ w2b,
    const int* __restrict__ offs, float* __restrict__ y) {
  int e = blockIdx.z;
  int aoff = offs[e];
  int cnt = offs[e + 1] - aoff;
  int m0 = blockIdx.y * 128;
  if (m0 >= cnt) return;
  int n0 = blockIdx.x * 128;

  __shared__ u16 As[2][128 * 64];
  __shared__ u16 Bs[2][128 * 64];

  int tid = threadIdx.x, lane = tid & 63, wid = tid >> 6;
  int l8 = lane >> 3, c8 = lane & 7;

  const u16* gA[4]; const u16* gB[4];
#pragma unroll
  for (int i = 0; i < 4; ++i) {
    int row = (i * 4 + wid) * 8 + l8;
    gA[i] = hidden + (size_t)(aoff + m0 + row) * ID + c8 * 8;   // slack rows keep this in-buffer
    gB[i] = w2b + ((size_t)e * HD + n0 + row) * ID + c8 * 8;
  }

  f32x4 acc[4][4];
#pragma unroll
  for (int m = 0; m < 4; ++m)
#pragma unroll
    for (int n = 0; n < 4; ++n) acc[m][n] = (f32x4){0.f, 0.f, 0.f, 0.f};

  auto stage = [&](int buf, int k0) {
#pragma unroll
    for (int i = 0; i < 4; ++i) {
      gld16(&As[buf][(i * 4 + wid) * 512], gA[i] + k0);
      gld16(&Bs[buf][(i * 4 + wid) * 512], gB[i] + k0);
    }
  };

  int lane15 = lane & 15, lq = lane >> 4;
  int wr = wid >> 1, wc = wid & 1;
  int arow = wr * 64, bcol = wc * 64;

  stage(0, 0);
  for (int t = 0; t < ID / 64; ++t) {
    __syncthreads();
    if (t < ID / 64 - 1) stage((t + 1) & 1, (t + 1) * 64);
    int buf = t & 1;
#pragma unroll
    for (int kk = 0; kk < 2; ++kk) {
      int ko = kk * 32 + lq * 8;
      s16x8 a[4], b[4];
#pragma unroll
      for (int m = 0; m < 4; ++m)
        a[m] = *(const s16x8*)&As[buf][(arow + m * 16 + lane15) * 64 + ko];
#pragma unroll
      for (int n = 0; n < 4; ++n)
        b[n] = *(const s16x8*)&Bs[buf][(bcol + n * 16 + lane15) * 64 + ko];
#pragma unroll
      for (int m = 0; m < 4; ++m)
#pragma unroll
        for (int n = 0; n < 4; ++n)
          acc[m][n] = __builtin_amdgcn_mfma_f32_16x16x32_bf16(a[m], b[n], acc[m][n], 0, 0, 0);
    }
  }

#pragma unroll
  for (int m = 0; m < 4; ++m)
#pragma unroll
    for (int j = 0; j < 4; ++j) {
      int grow = m0 + arow + m * 16 + lq * 4 + j;
      if (grow < cnt) {
        size_t rbase = (size_t)(aoff + grow) * HD + n0 + bcol;
#pragma unroll
        for (int n = 0; n < 4; ++n)
          y[rbase + n * 16 + lane15] = acc[m][n][j];
      }
    }
}

// ---------------- combine: out[t] = w0*y[pos0] + w1*y[pos1] ----------------

__global__ __launch_bounds__(256) void k_combine(
    const float* __restrict__ y, const int* __restrict__ pos,
    const float* __restrict__ tw, float* __restrict__ out) {
  int t = blockIdx.x;
  int c = threadIdx.x;   // 256 threads x float4 = 1024 floats = one token row
  int a0 = pos[t * 2], a1 = pos[t * 2 + 1];
  float w0 = tw[t * 2], w1 = tw[t * 2 + 1];
  float4 v0 = ((const float4*)(y + (size_t)a0 * HD))[c];
  float4 v1 = ((const float4*)(y + (size_t)a1 * HD))[c];
  float4 o;
  o.x = w0 * v0.x + w1 * v1.x;
  o.y = w0 * v0.y + w1 * v1.y;
  o.z = w0 * v0.z + w1 * v1.z;
  o.w = w0 * v0.w + w1 * v1.w;
  ((float4*)(out + (size_t)t * HD))[c] = o;
}

// ---------------- host ----------------

extern "C" void kernel_launch(void* const* d_in, const int* in_sizes, int n_in,
                              void* d_out, int out_size, void* d_ws, size_t ws_size,
                              hipStream_t stream) {
  const float* x  = (const float*)d_in[0];
  const float* wg = (const float*)d_in[1];
  const float* w1 = (const float*)d_in[2];
  const float* w2 = (const float*)d_in[3];
  const float* w3 = (const float*)d_in[4];
  float* out = (float*)d_out;

  char* p = (char*)d_ws;
  auto alloc = [&](size_t bytes) {
    char* r = p;
    p += (bytes + 255) & ~(size_t)255;
    return r;
  };
  u16*   xb      = (u16*)alloc((size_t)T_TOK * HD * 2);       // 16 MiB
  u16*   w1b     = (u16*)alloc((size_t)NE * HD * ID * 2);     // 64 MiB  [E][I][H]
  u16*   w3b     = (u16*)alloc((size_t)NE * HD * ID * 2);     // 64 MiB  [E][I][H]
  u16*   w2b     = (u16*)alloc((size_t)NE * HD * ID * 2);     // 64 MiB  [E][H][I]
  u16*   hidden  = (u16*)alloc((size_t)APAD * ID * 2);        // 129 MiB
  float* yb      = (float*)alloc((size_t)APAD * HD * 4);      // 64.5 MiB
  int*   tidx    = (int*)alloc(AK * 4);
  float* tw      = (float*)alloc(AK * 4);
  int*   list    = (int*)alloc(AK * 4);
  int*   pos     = (int*)alloc(AK * 4);
  int*   counts  = (int*)alloc(64);
  int*   offs    = (int*)alloc(64);
  int*   cursors = (int*)alloc(64);
  (void)ws_size; (void)in_sizes; (void)n_in; (void)out_size;

  k_init<<<1, 64, 0, stream>>>(counts);
  k_router<<<T_TOK / 4, 256, 0, stream>>>(x, wg, tidx, tw, counts);
  k_offsets<<<1, 64, 0, stream>>>(counts, offs, cursors);
  k_scatter<<<AK / 256, 256, 0, stream>>>(tidx, offs, cursors, list, pos);

  k_cvtx<<<(T_TOK * HD / 4) / 256, 256, 0, stream>>>(x, xb);
  dim3 g13(ID / 64, HD / 64, NE);
  k_tconv<<<g13, 256, 0, stream>>>(w1, w1b, HD, ID);   // [H][I] -> [I][H]
  k_tconv<<<g13, 256, 0, stream>>>(w3, w3b, HD, ID);
  dim3 g2(HD / 64, ID / 64, NE);
  k_tconv<<<g2, 256, 0, stream>>>(w2, w2b, ID, HD);    // [I][H] -> [H][I]

  dim3 gg1(ID / 64, T_TOK / 128, NE);
  k_gemm1<<<gg1, 256, 0, stream>>>(xb, w1b, w3b, list, offs, hidden);
  dim3 gg2(HD / 128, T_TOK / 128, NE);
  k_gemm2<<<gg2, 256, 0, stream>>>(hidden, w2b, offs, yb);
  k_combine<<<T_TOK, 256, 0, stream>>>(yb, pos, tw, out);
}

// Round 2
// 1114.387 us; speedup vs baseline: 1.1626x; 1.1626x over previous
//
#include <hip/hip_runtime.h>

typedef unsigned short u16;
typedef __attribute__((ext_vector_type(4))) float f32x4;
typedef __attribute__((ext_vector_type(8))) short s16x8;

#define T_TOK 8192
#define HD    1024
#define ID    4096
#define NE    8
#define AK    (T_TOK * 2)      // total assignments (top-2)
#define APAD  (AK + 128)       // slack rows so padded tile reads stay in-buffer

__device__ __forceinline__ u16 f2bf(float f) {
  unsigned u = __builtin_bit_cast(unsigned, f);
  u += 0x7FFFu + ((u >> 16) & 1u);   // round-to-nearest-even
  return (u16)(u >> 16);
}

__device__ __forceinline__ void gld16(u16* lds, const u16* g) {
  __builtin_amdgcn_global_load_lds(
      (const __attribute__((address_space(1))) unsigned int*)g,
      (__attribute__((address_space(3))) unsigned int*)lds, 16, 0, 0);
}

// ---------------- routing ----------------

__global__ void k_init(int* counts) {
  if (threadIdx.x < NE) counts[threadIdx.x] = 0;
}

__global__ __launch_bounds__(256) void k_router(
    const float* __restrict__ x, const float* __restrict__ wg,
    int* __restrict__ tidx, float* __restrict__ tw, int* __restrict__ counts) {
  __shared__ float wgs[NE * HD];            // transposed [e][h]
  int tid = threadIdx.x;
  for (int i = tid; i < NE * HD; i += 256) {
    int h = i >> 3, e = i & 7;
    wgs[e * HD + h] = wg[i];
  }
  __syncthreads();
  int lane = tid & 63, wid = tid >> 6;
  int t = blockIdx.x * 4 + wid;
  const float* xr = x + (size_t)t * HD;
  double acc[NE];
#pragma unroll
  for (int e = 0; e < NE; ++e) acc[e] = 0.0;
  for (int i = 0; i < HD / 64; ++i) {
    float xv = xr[lane + i * 64];
#pragma unroll
    for (int e = 0; e < NE; ++e)
      acc[e] += (double)xv * (double)wgs[e * HD + lane + i * 64];
  }
#pragma unroll
  for (int e = 0; e < NE; ++e)
    for (int s = 32; s >= 1; s >>= 1) acc[e] += __shfl_xor(acc[e], s, 64);
  // top-2 (first-index wins on ties, matching jax top_k)
  int e0 = 0; double m0 = acc[0];
  for (int e = 1; e < NE; ++e) if (acc[e] > m0) { m0 = acc[e]; e0 = e; }
  int e1 = -1; double m1 = -1e300;
  for (int e = 0; e < NE; ++e) if (e != e0 && acc[e] > m1) { m1 = acc[e]; e1 = e; }
  if (lane == 0) {
    double d = exp(m1 - m0);           // renormalized top-2 softmax weights
    tidx[t * 2] = e0; tidx[t * 2 + 1] = e1;
    tw[t * 2] = (float)(1.0 / (1.0 + d));
    tw[t * 2 + 1] = (float)(d / (1.0 + d));
    atomicAdd(&counts[e0], 1);
    atomicAdd(&counts[e1], 1);
  }
}

__global__ void k_offsets(const int* __restrict__ counts, int* offs, int* cursors) {
  if (threadIdx.x == 0) {
    int s = 0;
    for (int e = 0; e < NE; ++e) { offs[e] = s; s += counts[e]; }
    offs[NE] = s;
  }
  if (threadIdx.x < NE) cursors[threadIdx.x] = 0;
}

__global__ __launch_bounds__(256) void k_scatter(
    const int* __restrict__ tidx, const int* __restrict__ offs,
    int* cursors, int* __restrict__ list, int* __restrict__ pos) {
  int idx = blockIdx.x * 256 + threadIdx.x;
  if (idx >= AK) return;
  int e = tidx[idx];
  int p = atomicAdd(&cursors[e], 1);
  int a = offs[e] + p;
  list[a] = idx >> 1;
  pos[idx] = a;
}

// ---------------- fp32 -> bf16 conversion ----------------

__global__ __launch_bounds__(256) void k_cvtx(const float* __restrict__ in,
                                              u16* __restrict__ out) {
  int idx = blockIdx.x * 256 + threadIdx.x;   // one float4 each
  const float4* in4 = (const float4*)in;
  float4 v = in4[idx];
  ushort4 o;
  o.x = f2bf(v.x); o.y = f2bf(v.y); o.z = f2bf(v.z); o.w = f2bf(v.w);
  ((ushort4*)out)[idx] = o;
}

// [R][C] fp32 -> [C][R] bf16, per expert (blockIdx.z). Vectorized both sides:
// float4 global reads -> LDS transpose -> 16B short8 global stores.
__global__ __launch_bounds__(256) void k_tconv(const float* __restrict__ in,
                                               u16* __restrict__ out, int R, int C) {
  __shared__ u16 tile[64][72];               // +8 pad breaks write conflicts
  size_t base = (size_t)blockIdx.z * R * C;
  int r0 = blockIdx.y * 64, c0 = blockIdx.x * 64;
  int t = threadIdx.x;
  int rr = t >> 4;            // 0..15
  int cc = (t & 15) * 4;      // col chunk of 4
#pragma unroll
  for (int i = 0; i < 4; ++i) {
    int r = i * 16 + rr;
    float4 v = *(const float4*)&in[base + (size_t)(r0 + r) * C + c0 + cc];
    tile[cc + 0][r] = f2bf(v.x);
    tile[cc + 1][r] = f2bf(v.y);
    tile[cc + 2][r] = f2bf(v.z);
    tile[cc + 3][r] = f2bf(v.w);
  }
  __syncthreads();
  int c = t >> 3;             // 0..31
  int ch = (t & 7) * 8;       // 16B chunk along R
#pragma unroll
  for (int j = 0; j < 2; ++j) {
    int cr = j * 32 + c;
    *(s16x8*)&out[base + (size_t)(c0 + cr) * R + r0 + ch] =
        *(const s16x8*)&tile[cr][ch];
  }
}

// ---------------- GEMM1: hidden = silu(x@w1) * (x@w3), gathered rows ----------------
// tile 128(M) x 64(N=I) x 64(K=H); 4 waves 2x2, wave tile 64x32
// LDS XOR-swizzle (T2, rule #21): linear gld16 dest + inverse-swizzled global
// source chunk (c8^l8) + swizzled ds_read chunk ((kc)^(row&7)).

__global__ __launch_bounds__(256, 2) void k_gemm1(
    const u16* __restrict__ xb, const u16* __restrict__ w1b,
    const u16* __restrict__ w3b, const int* __restrict__ list,
    const int* __restrict__ offs, u16* __restrict__ hidden) {
  int e = blockIdx.z;
  int aoff = offs[e];
  int cnt = offs[e + 1] - aoff;
  int m0 = blockIdx.y * 128;
  if (m0 >= cnt) return;
  int n0 = blockIdx.x * 64;

  __shared__ u16 As[2][128 * 64];
  __shared__ u16 B1s[2][64 * 64];
  __shared__ u16 B3s[2][64 * 64];

  int tid = threadIdx.x, lane = tid & 63, wid = tid >> 6;
  int l8 = lane >> 3, c8 = lane & 7;
  int csrc = (c8 ^ l8) * 8;                 // pre-swizzled source chunk

  const u16* gA[4];
#pragma unroll
  for (int i = 0; i < 4; ++i) {
    int row = (i * 4 + wid) * 8 + l8;
    int rr = m0 + row; if (rr > cnt - 1) rr = cnt - 1;
    int tok = list[aoff + rr];
    gA[i] = xb + (size_t)tok * HD + csrc;
  }
  const u16* gB1[2]; const u16* gB3[2];
#pragma unroll
  for (int i = 0; i < 2; ++i) {
    int n = (i * 4 + wid) * 8 + l8;
    size_t roww = ((size_t)e * ID + (n0 + n)) * HD + csrc;
    gB1[i] = w1b + roww;
    gB3[i] = w3b + roww;
  }

  f32x4 acc1[4][2], acc3[4][2];
#pragma unroll
  for (int m = 0; m < 4; ++m)
#pragma unroll
    for (int n = 0; n < 2; ++n) {
      acc1[m][n] = (f32x4){0.f, 0.f, 0.f, 0.f};
      acc3[m][n] = (f32x4){0.f, 0.f, 0.f, 0.f};
    }

  auto stage = [&](int buf, int k0) {
#pragma unroll
    for (int i = 0; i < 4; ++i) gld16(&As[buf][(i * 4 + wid) * 512], gA[i] + k0);
#pragma unroll
    for (int i = 0; i < 2; ++i) {
      gld16(&B1s[buf][(i * 4 + wid) * 512], gB1[i] + k0);
      gld16(&B3s[buf][(i * 4 + wid) * 512], gB3[i] + k0);
    }
  };

  int lane15 = lane & 15, lq = lane >> 4;
  int sw8 = lane15 & 7;                     // row&7 of every fragment row
  int wr = wid >> 1, wc = wid & 1;
  int arow = wr * 64, bcol = wc * 32;

  stage(0, 0);
  for (int t = 0; t < HD / 64; ++t) {
    __syncthreads();                       // drains vmcnt -> buf[t&1] staged
    if (t < HD / 64 - 1) stage((t + 1) & 1, (t + 1) * 64);
    int buf = t & 1;
#pragma unroll
    for (int kk = 0; kk < 2; ++kk) {
      int ko = ((kk * 4 + lq) ^ sw8) * 8;  // swizzled physical chunk
      s16x8 a[4], b1[2], b3[2];
#pragma unroll
      for (int m = 0; m < 4; ++m)
        a[m] = *(const s16x8*)&As[buf][(arow + m * 16 + lane15) * 64 + ko];
#pragma unroll
      for (int n = 0; n < 2; ++n) {
        b1[n] = *(const s16x8*)&B1s[buf][(bcol + n * 16 + lane15) * 64 + ko];
        b3[n] = *(const s16x8*)&B3s[buf][(bcol + n * 16 + lane15) * 64 + ko];
      }
#pragma unroll
      for (int m = 0; m < 4; ++m)
#pragma unroll
        for (int n = 0; n < 2; ++n) {
          acc1[m][n] = __builtin_amdgcn_mfma_f32_16x16x32_bf16(a[m], b1[n], acc1[m][n], 0, 0, 0);
          acc3[m][n] = __builtin_amdgcn_mfma_f32_16x16x32_bf16(a[m], b3[n], acc3[m][n], 0, 0, 0);
        }
    }
  }

#pragma unroll
  for (int m = 0; m < 4; ++m)
#pragma unroll
    for (int j = 0; j < 4; ++j) {
      int grow = m0 + arow + m * 16 + lq * 4 + j;
      if (grow < cnt) {
        size_t rbase = (size_t)(aoff + grow) * ID + n0 + bcol;
#pragma unroll
        for (int n = 0; n < 2; ++n) {
          float v1 = acc1[m][n][j];
          float v3 = acc3[m][n][j];
          float s = v1 / (1.0f + __expf(-v1));
          hidden[rbase + n * 16 + lane15] = f2bf(s * v3);
        }
      }
    }
}

// ---------------- GEMM2: y = hidden @ w2 ----------------
// tile 128(M) x 128(N=H) x 64(K=I); 4 waves 2x2, wave tile 64x64; same swizzle

__global__ __launch_bounds__(256, 2) void k_gemm2(
    const u16* __restrict__ hidden, const u16* __restrict__ w2b,
    const int* __restrict__ offs, float* __restrict__ y) {
  int e = blockIdx.z;
  int aoff = offs[e];
  int cnt = offs[e + 1] - aoff;
  int m0 = blockIdx.y * 128;
  if (m0 >= cnt) return;
  int n0 = blockIdx.x * 128;

  __shared__ u16 As[2][128 * 64];
  __shared__ u16 Bs[2][128 * 64];

  int tid = threadIdx.x, lane = tid & 63, wid = tid >> 6;
  int l8 = lane >> 3, c8 = lane & 7;
  int csrc = (c8 ^ l8) * 8;

  const u16* gA[4]; const u16* gB[4];
#pragma unroll
  for (int i = 0; i < 4; ++i) {
    int row = (i * 4 + wid) * 8 + l8;
    gA[i] = hidden + (size_t)(aoff + m0 + row) * ID + csrc;   // slack rows keep this in-buffer
    gB[i] = w2b + ((size_t)e * HD + n0 + row) * ID + csrc;
  }

  f32x4 acc[4][4];
#pragma unroll
  for (int m = 0; m < 4; ++m)
#pragma unroll
    for (int n = 0; n < 4; ++n) acc[m][n] = (f32x4){0.f, 0.f, 0.f, 0.f};

  auto stage = [&](int buf, int k0) {
#pragma unroll
    for (int i = 0; i < 4; ++i) {
      gld16(&As[buf][(i * 4 + wid) * 512], gA[i] + k0);
      gld16(&Bs[buf][(i * 4 + wid) * 512], gB[i] + k0);
    }
  };

  int lane15 = lane & 15, lq = lane >> 4;
  int sw8 = lane15 & 7;
  int wr = wid >> 1, wc = wid & 1;
  int arow = wr * 64, bcol = wc * 64;

  stage(0, 0);
  for (int t = 0; t < ID / 64; ++t) {
    __syncthreads();
    if (t < ID / 64 - 1) stage((t + 1) & 1, (t + 1) * 64);
    int buf = t & 1;
#pragma unroll
    for (int kk = 0; kk < 2; ++kk) {
      int ko = ((kk * 4 + lq) ^ sw8) * 8;
      s16x8 a[4], b[4];
#pragma unroll
      for (int m = 0; m < 4; ++m)
        a[m] = *(const s16x8*)&As[buf][(arow + m * 16 + lane15) * 64 + ko];
#pragma unroll
      for (int n = 0; n < 4; ++n)
        b[n] = *(const s16x8*)&Bs[buf][(bcol + n * 16 + lane15) * 64 + ko];
#pragma unroll
      for (int m = 0; m < 4; ++m)
#pragma unroll
        for (int n = 0; n < 4; ++n)
          acc[m][n] = __builtin_amdgcn_mfma_f32_16x16x32_bf16(a[m], b[n], acc[m][n], 0, 0, 0);
    }
  }

#pragma unroll
  for (int m = 0; m < 4; ++m)
#pragma unroll
    for (int j = 0; j < 4; ++j) {
      int grow = m0 + arow + m * 16 + lq * 4 + j;
      if (grow < cnt) {
        size_t rbase = (size_t)(aoff + grow) * HD + n0 + bcol;
#pragma unroll
        for (int n = 0; n < 4; ++n)
          y[rbase + n * 16 + lane15] = acc[m][n][j];
      }
    }
}

// ---------------- combine: out[t] = w0*y[pos0] + w1*y[pos1] ----------------

__global__ __launch_bounds__(256) void k_combine(
    const float* __restrict__ y, const int* __restrict__ pos,
    const float* __restrict__ tw, float* __restrict__ out) {
  int t = blockIdx.x;
  int c = threadIdx.x;   // 256 threads x float4 = 1024 floats = one token row
  int a0 = pos[t * 2], a1 = pos[t * 2 + 1];
  float w0 = tw[t * 2], w1 = tw[t * 2 + 1];
  float4 v0 = ((const float4*)(y + (size_t)a0 * HD))[c];
  float4 v1 = ((const float4*)(y + (size_t)a1 * HD))[c];
  float4 o;
  o.x = w0 * v0.x + w1 * v1.x;
  o.y = w0 * v0.y + w1 * v1.y;
  o.z = w0 * v0.z + w1 * v1.z;
  o.w = w0 * v0.w + w1 * v1.w;
  ((float4*)(out + (size_t)t * HD))[c] = o;
}

// ---------------- host ----------------

extern "C" void kernel_launch(void* const* d_in, const int* in_sizes, int n_in,
                              void* d_out, int out_size, void* d_ws, size_t ws_size,
                              hipStream_t stream) {
  const float* x  = (const float*)d_in[0];
  const float* wg = (const float*)d_in[1];
  const float* w1 = (const float*)d_in[2];
  const float* w2 = (const float*)d_in[3];
  const float* w3 = (const float*)d_in[4];
  float* out = (float*)d_out;

  char* p = (char*)d_ws;
  auto alloc = [&](size_t bytes) {
    char* r = p;
    p += (bytes + 255) & ~(size_t)255;
    return r;
  };
  u16*   xb      = (u16*)alloc((size_t)T_TOK * HD * 2);       // 16 MiB
  u16*   w1b     = (u16*)alloc((size_t)NE * HD * ID * 2);     // 64 MiB  [E][I][H]
  u16*   w3b     = (u16*)alloc((size_t)NE * HD * ID * 2);     // 64 MiB  [E][I][H]
  u16*   w2b     = (u16*)alloc((size_t)NE * HD * ID * 2);     // 64 MiB  [E][H][I]
  u16*   hidden  = (u16*)alloc((size_t)APAD * ID * 2);        // 129 MiB
  float* yb      = (float*)alloc((size_t)APAD * HD * 4);      // 64.5 MiB
  int*   tidx    = (int*)alloc(AK * 4);
  float* tw      = (float*)alloc(AK * 4);
  int*   list    = (int*)alloc(AK * 4);
  int*   pos     = (int*)alloc(AK * 4);
  int*   counts  = (int*)alloc(64);
  int*   offs    = (int*)alloc(64);
  int*   cursors = (int*)alloc(64);
  (void)ws_size; (void)in_sizes; (void)n_in; (void)out_size;

  k_init<<<1, 64, 0, stream>>>(counts);
  k_router<<<T_TOK / 4, 256, 0, stream>>>(x, wg, tidx, tw, counts);
  k_offsets<<<1, 64, 0, stream>>>(counts, offs, cursors);
  k_scatter<<<AK / 256, 256, 0, stream>>>(tidx, offs, cursors, list, pos);

  k_cvtx<<<(T_TOK * HD / 4) / 256, 256, 0, stream>>>(x, xb);
  dim3 g13(ID / 64, HD / 64, NE);
  k_tconv<<<g13, 256, 0, stream>>>(w1, w1b, HD, ID);   // [H][I] -> [I][H]
  k_tconv<<<g13, 256, 0, stream>>>(w3, w3b, HD, ID);
  dim3 g2(HD / 64, ID / 64, NE);
  k_tconv<<<g2, 256, 0, stream>>>(w2, w2b, ID, HD);    // [I][H] -> [H][I]

  dim3 gg1(ID / 64, T_TOK / 128, NE);
  k_gemm1<<<gg1, 256, 0, stream>>>(xb, w1b, w3b, list, offs, hidden);
  dim3 gg2(HD / 128, T_TOK / 128, NE);
  k_gemm2<<<gg2, 256, 0, stream>>>(hidden, w2b, offs, yb);
  k_combine<<<T_TOK, 256, 0, stream>>>(yb, pos, tw, out);
}